// Round 6
// baseline (886.781 us; speedup 1.0000x reference)
//
#include <hip/hip_runtime.h>
#include <hip/hip_bf16.h>

#define F_DIM 64
#define H_DIM 128
#define K1    64       // per-slot K: x[e1] part, computed in f32
#define K2    96       // per-edge K: x[e0](64) + ppf(4) + zero-pad -> 96

typedef __attribute__((ext_vector_type(8))) short short8;   // 8 bf16 (mfma A/B frag)
typedef __attribute__((ext_vector_type(4))) float f32x4;    // mfma C/D frag

__device__ __forceinline__ unsigned short f2bf(float f) {
    __hip_bfloat16 h = __float2bfloat16(f);
    return __builtin_bit_cast(unsigned short, h);
}

__device__ __forceinline__ short8 pack_bf8(f32x4 a, f32x4 b) {
    union { uint4 u; short8 s; } r;
    r.u.x = (unsigned)f2bf(a.x) | ((unsigned)f2bf(a.y) << 16);
    r.u.y = (unsigned)f2bf(a.z) | ((unsigned)f2bf(a.w) << 16);
    r.u.z = (unsigned)f2bf(b.x) | ((unsigned)f2bf(b.y) << 16);
    r.u.w = (unsigned)f2bf(b.z) | ((unsigned)f2bf(b.w) << 16);
    return r.s;
}

__device__ __forceinline__ float angle3(float ax, float ay, float az,
                                        float bx, float by, float bz) {
    float cx = ay*bz - az*by;
    float cy = az*bx - ax*bz;
    float cz = ax*by - ay*bx;
    float cn = sqrtf(cx*cx + cy*cy + cz*cz);
    float d  = ax*bx + ay*by + az*bz;
    return atan2f(cn, d);
}

// fused init: w1t f32 [128][64] (=W[0:64]^T), wt2 bf16 [128][96] (=W[64:132]^T zero-pad),
//             node2slot scatter, cnt zero
__global__ void setup_kernel(const float* __restrict__ W, const int* __restrict__ idx,
                             float* __restrict__ w1t, unsigned short* __restrict__ wt2,
                             int* __restrict__ node2slot, int* __restrict__ cnt, int S) {
    int g = blockIdx.x * blockDim.x + threadIdx.x;
    if (g < H_DIM * K1) {                         // w1t[n][k] = W[k][n]
        int n = g >> 6, k = g & 63;
        w1t[g] = W[k * H_DIM + n];
    }
    int g2 = g - H_DIM * K1;
    if (g2 >= 0 && g2 < H_DIM * K2) {             // wt2[n][k]: k<64 -> W[64+k][n], 64..67 -> W[128+k-64][n], else 0
        int n = g2 / K2, k = g2 % K2;
        float v = (k < 64) ? W[(64 + k) * H_DIM + n]
                : (k < 68) ? W[(128 + (k - 64)) * H_DIM + n] : 0.f;
        wt2[g2] = f2bf(v);
    }
    int g3 = g2 - H_DIM * K2;
    if (g3 >= 0 && g3 < S) node2slot[idx[g3]] = g3;   // dup idx: any winner canonical
    int g4 = g3 - S;
    if (g4 >= 0 && g4 < S) cnt[g4] = 0;
}

// ---- counting sort of edges by target slot ----
__global__ void hist_kernel(const int* __restrict__ edge, const int* __restrict__ node2slot,
                            int* __restrict__ cnt, int E) {
    int e = blockIdx.x * blockDim.x + threadIdx.x;
    if (e < E) atomicAdd(&cnt[node2slot[edge[E + e]]], 1);
}

__global__ void scan1(const int* __restrict__ cnt, int* __restrict__ off,
                      int* __restrict__ bsum, int S) {
    __shared__ int wsum[16];
    const int lane = threadIdx.x & 63, wv = threadIdx.x >> 6;
    int i = blockIdx.x * 1024 + (int)threadIdx.x;
    int v = (i < S) ? cnt[i] : 0;
    int acc = v;
    #pragma unroll
    for (int d = 1; d < 64; d <<= 1) {
        int t = __shfl_up(acc, d, 64);
        if (lane >= d) acc += t;
    }
    if (lane == 63) wsum[wv] = acc;
    __syncthreads();
    if (threadIdx.x == 0) {
        int run = 0;
        #pragma unroll
        for (int j = 0; j < 16; ++j) { int t = wsum[j]; wsum[j] = run; run += t; }
        bsum[blockIdx.x] = run;
    }
    __syncthreads();
    if (i < S) off[i] = wsum[wv] + acc - v;
}

__global__ void scan2(int* __restrict__ bsum, int nb) {
    if (threadIdx.x == 0 && blockIdx.x == 0) {
        int run = 0;
        for (int j = 0; j < nb; ++j) { int t = bsum[j]; bsum[j] = run; run += t; }
    }
}

__global__ void scan3(int* __restrict__ off, const int* __restrict__ bsum, int S) {
    int i = blockIdx.x * 1024 + (int)threadIdx.x;
    if (i < S) off[i] += bsum[blockIdx.x];
}

// stores e0 VALUE (not edge id) at sorted position — removes a random gather from the hot kernel
__global__ void scatter_perm(const int* __restrict__ edge, const int* __restrict__ node2slot,
                             int* __restrict__ off_mut, int* __restrict__ perm, int E) {
    int e = blockIdx.x * blockDim.x + threadIdx.x;
    if (e < E) {
        int s = node2slot[edge[E + e]];
        int p = atomicAdd(&off_mut[s], 1);
        if (p >= 0 && p < E) perm[p] = edge[e];   // e0 value
    }
}

// ---- wave-per-slot: no LDS, no barriers, no aggregation atomics ----
__global__ __launch_bounds__(256, 4)
void edge_wave_kernel(const float* __restrict__ x, const float* __restrict__ pos,
                      const float* __restrict__ normal, const float* __restrict__ w1t,
                      const unsigned short* __restrict__ wt2, const float* __restrict__ bias,
                      const int* __restrict__ idx, const int* __restrict__ perm,
                      const int* __restrict__ cnt, const int* __restrict__ off_inc,
                      float* __restrict__ out, int E, int S, int N) {
    const int wv   = threadIdx.x >> 6;
    const int lane = threadIdx.x & 63;
    const int s = blockIdx.x * 4 + wv;
    if (s >= S) return;
    const int l15  = lane & 15;
    const int quad = lane >> 4;
    const int colA = (quad * 2) * 16 + l15;    // this lane writes cols colA, colA+16
    const int colB = colA + 16;
    float* orow = out + (size_t)s * H_DIM;

    int count = cnt[s];
    if (count <= 0) { orow[colA] = 0.f; orow[colB] = 0.f; return; }
    int start = off_inc[s] - count;            // exclusive offset (off is inclusive post-scatter)
    if (start < 0) start = 0;
    if (start >= E) start = E - 1;
    if (start + count > E) count = E - start;

    const int e1 = idx[s];                     // e1 is CONSTANT over the slot's edges

    // ---- per-slot constant (exact f32): c[col] = dot(x[e1], W[0:64,col]) + bias[col] ----
    float cA = bias[colA], cB = bias[colB];
    {
        const f32x4* xv = (const f32x4*)(x + (size_t)e1 * F_DIM);
        const f32x4* wA = (const f32x4*)(w1t + (size_t)colA * K1);
        const f32x4* wB = (const f32x4*)(w1t + (size_t)colB * K1);
        #pragma unroll
        for (int kk = 0; kk < 16; ++kk) {
            f32x4 xq = xv[kk], aq = wA[kk], bq = wB[kk];
            cA += xq.x*aq.x + xq.y*aq.y + xq.z*aq.z + xq.w*aq.w;
            cB += xq.x*bq.x + xq.y*bq.y + xq.z*bq.z + xq.w*bq.w;
        }
    }

    const float p1x = pos[3*e1], p1y = pos[3*e1+1], p1z = pos[3*e1+2];
    const float n1x = normal[3*e1], n1y = normal[3*e1+1], n1z = normal[3*e1+2];

    float rmax[8];
    #pragma unroll
    for (int nt = 0; nt < 8; ++nt) rmax[nt] = -INFINITY;
    const f32x4 z4 = {0.f, 0.f, 0.f, 0.f};

    for (int base = 0; base < count; base += 16) {
        // A-fragment: row = l15 (this lane's edge), k-slice = quad*8; pads duplicate first edge
        int gp = (base + l15 < count) ? (start + base + l15) : start;
        int e0 = perm[gp];
        if (e0 < 0 || e0 >= N) e0 = 0;
        const f32x4* xr  = (const f32x4*)(x + (size_t)e0 * F_DIM + quad * 8);        // k 0..31
        short8 a0 = pack_bf8(xr[0], xr[1]);
        const f32x4* xr2 = (const f32x4*)(x + (size_t)e0 * F_DIM + 32 + quad * 8);   // k 32..63
        short8 a1 = pack_bf8(xr2[0], xr2[1]);
        short8 a2 = (short8){0,0,0,0,0,0,0,0};                                       // k 64..95
        if (quad == 0) {           // only quad 0's slice (k 64..71) is nonzero: [ppf0..3, 0,0,0,0]
            float px = pos[3*e0]   - p1x;
            float py = pos[3*e0+1] - p1y;
            float pz = pos[3*e0+2] - p1z;
            float n0x = normal[3*e0], n0y = normal[3*e0+1], n0z = normal[3*e0+2];
            f32x4 pq;
            pq.x = sqrtf(px*px + py*py + pz*pz);
            pq.y = angle3(n1x,n1y,n1z, px,py,pz);
            pq.z = angle3(n0x,n0y,n0z, px,py,pz);
            pq.w = angle3(n1x,n1y,n1z, n0x,n0y,n0z);
            a2 = pack_bf8(pq, z4);
        }
        #pragma unroll
        for (int nt = 0; nt < 8; ++nt) {
            const unsigned short* wr = wt2 + (size_t)(nt * 16 + l15) * K2 + quad * 8;
            short8 b0 = *(const short8*)(wr);
            short8 b1 = *(const short8*)(wr + 32);
            short8 b2 = *(const short8*)(wr + 64);
            f32x4 t = __builtin_amdgcn_mfma_f32_16x16x32_bf16(a0, b0, z4, 0, 0, 0);
            t = __builtin_amdgcn_mfma_f32_16x16x32_bf16(a1, b1, t, 0, 0, 0);
            t = __builtin_amdgcn_mfma_f32_16x16x32_bf16(a2, b2, t, 0, 0, 0);
            rmax[nt] = fmaxf(rmax[nt], fmaxf(fmaxf(t[0], t[1]), fmaxf(t[2], t[3])));
        }
    }

    // cross-quad reduction: rows quad*4+r live in quads 0..3 -> combine
    #pragma unroll
    for (int nt = 0; nt < 8; ++nt) {
        rmax[nt] = fmaxf(rmax[nt], __shfl_xor(rmax[nt], 16, 64));
        rmax[nt] = fmaxf(rmax[nt], __shfl_xor(rmax[nt], 32, 64));
    }
    orow[colA] = fmaxf(rmax[quad * 2]     + cA, 0.f);
    orow[colB] = fmaxf(rmax[quad * 2 + 1] + cB, 0.f);
}

// duplicate-idx fixup (writes only non-canonical rows, reads only canonical) + pos gather
__global__ void finalize(const int* __restrict__ idx, const int* __restrict__ node2slot,
                         const float* __restrict__ pos, float* __restrict__ out, int S) {
    int g = blockIdx.x * blockDim.x + threadIdx.x;
    int total = S * H_DIM;
    if (g < total) {
        int s = g >> 7, c = g & 127;
        int node = idx[s];
        int sp = node2slot[node];
        if (sp != s) out[g] = out[(size_t)sp * H_DIM + c];
    } else if (g < total + 3 * S) {
        int g2 = g - total;
        int s = g2 / 3, j = g2 - 3 * s;
        out[total + g2] = pos[(size_t)idx[s] * 3 + j];
    }
}

extern "C" void kernel_launch(void* const* d_in, const int* in_sizes, int n_in,
                              void* d_out, int out_size, void* d_ws, size_t ws_size,
                              hipStream_t stream) {
    const float* x      = (const float*)d_in[0];
    const float* pos    = (const float*)d_in[1];
    const float* normal = (const float*)d_in[2];
    const float* W      = (const float*)d_in[3];
    const float* b      = (const float*)d_in[4];
    const int*   edge   = (const int*)d_in[5];
    const int*   idx    = (const int*)d_in[6];

    const int H = in_sizes[4];            // 128
    const int K = in_sizes[3] / H;        // 132
    const int F = (K - 4) / 2;            // 64
    const int N = in_sizes[0] / F;        // 100000
    const int E = in_sizes[5] / 2;        // 800000
    const int S = in_sizes[6];            // 25000

    // ws: w1t f32[128*64] | wt2 bf16[128*96] | node2slot[N] | cnt[S] | off[S] | bsum(pad 128B) | perm[E]
    char* w = (char*)d_ws;
    float* w1t = (float*)w;                   w += (size_t)H_DIM * K1 * sizeof(float);
    unsigned short* wt2 = (unsigned short*)w; w += (size_t)H_DIM * K2 * sizeof(unsigned short);
    int* node2slot = (int*)w;                 w += (size_t)N * sizeof(int);
    int* cnt = (int*)w;                       w += (size_t)S * sizeof(int);
    int* off = (int*)w;                       w += (size_t)S * sizeof(int);
    int* bsum = (int*)w;                      w += 128;
    int* perm = (int*)w;
    float* out = (float*)d_out;

    const int nb = (S + 1023) / 1024;
    const int setup_total = H_DIM * K1 + H_DIM * K2 + 2 * S;

    hipMemsetAsync(perm, 0, (size_t)E * sizeof(int), stream);   // safety: gaps -> node 0 (clamped)
    setup_kernel<<<(setup_total + 255) / 256, 256, 0, stream>>>(W, idx, w1t, wt2, node2slot, cnt, S);
    hist_kernel<<<(E + 255) / 256, 256, 0, stream>>>(edge, node2slot, cnt, E);
    scan1<<<nb, 1024, 0, stream>>>(cnt, off, bsum, S);
    scan2<<<1, 64, 0, stream>>>(bsum, nb);
    scan3<<<nb, 1024, 0, stream>>>(off, bsum, S);
    scatter_perm<<<(E + 255) / 256, 256, 0, stream>>>(edge, node2slot, off, perm, E);
    edge_wave_kernel<<<(S + 3) / 4, 256, 0, stream>>>(x, pos, normal, w1t, wt2, b,
                                                      idx, perm, cnt, off, out, E, S, N);
    finalize<<<(S * H + 3 * S + 255) / 256, 256, 0, stream>>>(idx, node2slot, pos, out, S);
}